// Round 1
// baseline (446.819 us; speedup 1.0000x reference)
//
#include <hip/hip_runtime.h>
#include <hip/hip_bf16.h>

// LRRNN: B=64, dz=16, K=16, N=1024, dx=128, T=500 (T read from input 8).
// One block per batch b (64 blocks, structural: N-reduction must be intra-block
// and MFMA needs 16 columns = the 16 k's of one batch). 4 waves x 256 N-rows.
// All GEMMs via mfma 16x16x16 bf16; C/D layout == B-operand layout lets
// X-acc -> relu -> pack feed n@R directly, and z' feed next m@z + readout.

typedef __attribute__((ext_vector_type(4))) short short4v;
typedef __attribute__((ext_vector_type(4))) float float4v;

#define BB 64
#define DZ 16
#define KC 16
#define NN 1024
#define DX 128

union FragAB {
  short4v s;
  __hip_bfloat162 h2[2];
};

__device__ inline short4v pack_bf16x4(float a, float b, float c, float d) {
  FragAB u;
  u.h2[0] = __float22bfloat162_rn(make_float2(a, b));
  u.h2[1] = __float22bfloat162_rn(make_float2(c, d));
  return u.s;
}

__device__ inline float4v mfma_bf16(short4v a, short4v b, float4v c) {
#if __has_builtin(__builtin_amdgcn_mfma_f32_16x16x16bf16_1k)
  return __builtin_amdgcn_mfma_f32_16x16x16bf16_1k(a, b, c, 0, 0, 0);
#elif __has_builtin(__builtin_amdgcn_mfma_f32_16x16x16_bf16)
  return __builtin_amdgcn_mfma_f32_16x16x16_bf16(a, b, c, 0, 0, 0);
#else
  float4v d;
  asm("v_mfma_f32_16x16x16_bf16 %0, %1, %2, %3"
      : "=v"(d) : "v"(a), "v"(b), "v"(c));
  return d;
#endif
}

__global__ __launch_bounds__(256, 1)
void lrrnn_fused(const float* __restrict__ z0, const float* __restrict__ Adec,
                 const float* __restrict__ nmat, const float* __restrict__ mmat,
                 const float* __restrict__ hvec, const float* __restrict__ hzvec,
                 const float* __restrict__ Bobs, const float* __restrict__ Bias,
                 const int* __restrict__ Tptr, float* __restrict__ out)
{
  const int T    = Tptr[0];
  const int b    = blockIdx.x;
  const int tid  = threadIdx.x;
  const int wave = tid >> 6;
  const int lane = tid & 63;
  const int g    = lane >> 4;   // 0..3  (quad group)
  const int c    = lane & 15;   // 0..15 (column / row-in-tile)

  // double-buffered per-wave partials of n@R (4 f32/lane)
  __shared__ float4v part[2][4][64];

  // ---- one-time fragment preload (all weights shared across blocks; L2/L3) ----
  // m A-frag: A[row=c][k=4g+j] = m[(rowbase+c)*16 + 4g+j]
  // n A-frag: A[row(z)=c][k=4g+j] = n[c*1024 + rowbase + 4g+j]
  // negH C-frag: C[row=4g+r][col] = -h[rowbase + 4g+r]
  FragAB mf[16], nf[16];
  float4v negH[16];
#pragma unroll
  for (int i = 0; i < 16; ++i) {
    const int rowbase = wave * 256 + i * 16;
    float4v mv = *(const float4v*)(mmat + (rowbase + c) * DZ + g * 4);
    mf[i].s = pack_bf16x4(mv[0], mv[1], mv[2], mv[3]);
    float4v nv = *(const float4v*)(nmat + c * NN + rowbase + g * 4);
    nf[i].s = pack_bf16x4(nv[0], nv[1], nv[2], nv[3]);
    float4v hv = *(const float4v*)(hvec + rowbase + g * 4);
    negH[i][0] = -hv[0]; negH[i][1] = -hv[1];
    negH[i][2] = -hv[2]; negH[i][3] = -hv[3];
  }

  // decay / bias-z frags (C-layout rows = z = 4g+r)
  const float4v Af  = *(const float4v*)(Adec + g * 4);
  const float4v hzf = *(const float4v*)(hzvec + g * 4);

  // readout: wave covers x in [32w, 32w+32), 2 tiles of 16
  // BobsT A-frag: A[row=x=c][k=z=4g+j] = Bobs[(4g+j)*128 + x]
  FragAB bobsF[2];
  float4v biasF[2];
#pragma unroll
  for (int xt = 0; xt < 2; ++xt) {
    const int xb = wave * 32 + xt * 16;
    bobsF[xt].s = pack_bf16x4(Bobs[(4 * g + 0) * DX + xb + c],
                              Bobs[(4 * g + 1) * DX + xb + c],
                              Bobs[(4 * g + 2) * DX + xb + c],
                              Bobs[(4 * g + 3) * DX + xb + c]);
    biasF[xt] = *(const float4v*)(Bias + xb + g * 4);
  }

  // z state: f32 master frag (C-layout) + bf16 B-frag
  float4v zf;
#pragma unroll
  for (int j = 0; j < 4; ++j)
    zf[j] = z0[b * DZ * KC + (g * 4 + j) * KC + c];
  FragAB zb;
  zb.s = pack_bf16x4(zf[0], zf[1], zf[2], zf[3]);

  // output element offsets: out[((b*128+x)*T + t)*16 + k]
  unsigned oof[2][4];
#pragma unroll
  for (int xt = 0; xt < 2; ++xt)
#pragma unroll
    for (int rr = 0; rr < 4; ++rr) {
      const int x = wave * 32 + xt * 16 + g * 4 + rr;
      oof[xt][rr] = (unsigned)(b * DX + x) * (unsigned)T * KC + c;
    }

  for (int t = 0; t < T; ++t) {
    // ---- X = m@z - h ; R = relu(X) ; zacc += n@R  (2 indep acc chains) ----
    float4v acc0 = {0.f, 0.f, 0.f, 0.f};
    float4v acc1 = {0.f, 0.f, 0.f, 0.f};
#pragma unroll
    for (int i = 0; i < 16; ++i) {
      float4v xv = mfma_bf16(mf[i].s, zb.s, negH[i]);
      short4v R = pack_bf16x4(fmaxf(xv[0], 0.f), fmaxf(xv[1], 0.f),
                              fmaxf(xv[2], 0.f), fmaxf(xv[3], 0.f));
      if (i & 1) acc1 = mfma_bf16(nf[i].s, R, acc1);
      else       acc0 = mfma_bf16(nf[i].s, R, acc0);
    }
    const float4v zp = acc0 + acc1;

    // ---- cross-wave reduce (double-buffered, 1 barrier/step) ----
    part[t & 1][wave][lane] = zp;
    __syncthreads();
    const float4v p0 = part[t & 1][0][lane];
    const float4v p1 = part[t & 1][1][lane];
    const float4v p2 = part[t & 1][2][lane];
    const float4v p3 = part[t & 1][3][lane];
    const float4v tot = (p0 + p1) + (p2 + p3);

    // z' = A*z + tot + hz   (identical in every wave -> consistent zb)
#pragma unroll
    for (int j = 0; j < 4; ++j)
      zf[j] = fmaf(Af[j], zf[j], tot[j] + hzf[j]);
    zb.s = pack_bf16x4(zf[0], zf[1], zf[2], zf[3]);

    // ---- fused readout: out[b, x, t, k] = BobsT@z' + Bias ----
#pragma unroll
    for (int xt = 0; xt < 2; ++xt) {
      float4v o = mfma_bf16(bobsF[xt].s, zb.s, biasF[xt]);
#pragma unroll
      for (int rr = 0; rr < 4; ++rr)
        out[oof[xt][rr] + (unsigned)t * KC] = o[rr];
    }
  }
}

extern "C" void kernel_launch(void* const* d_in, const int* in_sizes, int n_in,
                              void* d_out, int out_size, void* d_ws, size_t ws_size,
                              hipStream_t stream) {
  const float* z0   = (const float*)d_in[0];
  const float* A    = (const float*)d_in[1];
  const float* nmat = (const float*)d_in[2];
  const float* mmat = (const float*)d_in[3];
  const float* h    = (const float*)d_in[4];
  const float* hz   = (const float*)d_in[5];
  const float* Bobs = (const float*)d_in[6];
  const float* Bias = (const float*)d_in[7];
  const int*   T    = (const int*)d_in[8];
  (void)in_sizes; (void)n_in; (void)out_size; (void)d_ws; (void)ws_size;
  lrrnn_fused<<<dim3(BB), dim3(256), 0, stream>>>(
      z0, A, nmat, mmat, h, hz, Bobs, Bias, T, (float*)d_out);
}

// Round 2
// 433.248 us; speedup vs baseline: 1.0313x; 1.0313x over previous
//
#include <hip/hip_runtime.h>
#include <hip/hip_bf16.h>

// LRRNN: B=64, dz=16, K=16, N=1024, dx=128, T=500 (T read from input 8).
// 64 blocks (structural: 16 MFMA columns = 16 sequences of one batch; the
// N=1024 reduction is intra-block). 8 waves x 128 N-rows each -> 2 waves/SIMD
// so dependency stalls of one wave are filled by the other.
// All GEMMs via mfma 16x16x16 bf16; C/D layout == B-operand layout lets
// X-acc -> relu -> pack feed n@R directly, and z' feed next m@z + readout.

typedef __attribute__((ext_vector_type(4))) short short4v;
typedef __attribute__((ext_vector_type(4))) float float4v;

#define BB 64
#define DZ 16
#define KC 16
#define NN 1024
#define DX 128
#define NW 8          // waves per block
#define ITER (NN / (16 * NW))   // 8 row-tiles per wave

union FragAB {
  short4v s;
  __hip_bfloat162 h2[2];
};

__device__ inline short4v pack_bf16x4(float a, float b, float c, float d) {
  FragAB u;
  u.h2[0] = __float22bfloat162_rn(make_float2(a, b));
  u.h2[1] = __float22bfloat162_rn(make_float2(c, d));
  return u.s;
}

__device__ inline float4v mfma_bf16(short4v a, short4v b, float4v c) {
#if __has_builtin(__builtin_amdgcn_mfma_f32_16x16x16bf16_1k)
  return __builtin_amdgcn_mfma_f32_16x16x16bf16_1k(a, b, c, 0, 0, 0);
#elif __has_builtin(__builtin_amdgcn_mfma_f32_16x16x16_bf16)
  return __builtin_amdgcn_mfma_f32_16x16x16_bf16(a, b, c, 0, 0, 0);
#else
  float4v d;
  asm("v_mfma_f32_16x16x16_bf16 %0, %1, %2, %3"
      : "=v"(d) : "v"(a), "v"(b), "v"(c));
  return d;
#endif
}

__global__ __launch_bounds__(64 * NW, 2)
void lrrnn_fused(const float* __restrict__ z0, const float* __restrict__ Adec,
                 const float* __restrict__ nmat, const float* __restrict__ mmat,
                 const float* __restrict__ hvec, const float* __restrict__ hzvec,
                 const float* __restrict__ Bobs, const float* __restrict__ Bias,
                 const int* __restrict__ Tptr, float* __restrict__ out)
{
  const int T    = Tptr[0];
  const int b    = blockIdx.x;
  const int tid  = threadIdx.x;
  const int wave = tid >> 6;
  const int lane = tid & 63;
  const int g    = lane >> 4;   // 0..3  (quad group)
  const int c    = lane & 15;   // 0..15 (column / row-in-tile)

  // double-buffered per-wave partials of n@R (4 f32/lane) -> 16 KB
  __shared__ float4v part[2][NW][64];

  // ---- one-time fragment preload (weights shared across blocks; L2-resident) ----
  // m A-frag: A[row=c][k=4g+j] = m[(rowbase+c)*16 + 4g+j]
  // n A-frag: A[row(z)=c][k=4g+j] = n[c*1024 + rowbase + 4g+j]
  // negH C-frag: C[row=4g+r][col] = -h[rowbase + 4g+r]
  FragAB mf[ITER], nf[ITER];
  float4v negH[ITER];
#pragma unroll
  for (int i = 0; i < ITER; ++i) {
    const int rowbase = wave * (16 * ITER) + i * 16;
    float4v mv = *(const float4v*)(mmat + (rowbase + c) * DZ + g * 4);
    mf[i].s = pack_bf16x4(mv[0], mv[1], mv[2], mv[3]);
    float4v nv = *(const float4v*)(nmat + c * NN + rowbase + g * 4);
    nf[i].s = pack_bf16x4(nv[0], nv[1], nv[2], nv[3]);
    float4v hv = *(const float4v*)(hvec + rowbase + g * 4);
    negH[i][0] = -hv[0]; negH[i][1] = -hv[1];
    negH[i][2] = -hv[2]; negH[i][3] = -hv[3];
  }

  // decay / bias-z frags (C-layout rows = z = 4g+r)
  const float4v Af  = *(const float4v*)(Adec + g * 4);
  const float4v hzf = *(const float4v*)(hzvec + g * 4);

  // readout: wave covers x in [16w, 16w+16) -> one 16x16 tile
  // BobsT A-frag: A[row=x=c][k=z=4g+j] = Bobs[(4g+j)*128 + x]
  FragAB bobsF;
  float4v biasF;
  {
    const int xb = wave * 16;
    bobsF.s = pack_bf16x4(Bobs[(4 * g + 0) * DX + xb + c],
                          Bobs[(4 * g + 1) * DX + xb + c],
                          Bobs[(4 * g + 2) * DX + xb + c],
                          Bobs[(4 * g + 3) * DX + xb + c]);
    biasF = *(const float4v*)(Bias + xb + g * 4);
  }

  // z state: f32 master frag (C-layout) + bf16 B-frag
  float4v zf;
#pragma unroll
  for (int j = 0; j < 4; ++j)
    zf[j] = z0[b * DZ * KC + (g * 4 + j) * KC + c];
  FragAB zb;
  zb.s = pack_bf16x4(zf[0], zf[1], zf[2], zf[3]);

  // output element offsets: out[((b*128+x)*T + t)*16 + k]
  unsigned oof[4];
#pragma unroll
  for (int rr = 0; rr < 4; ++rr) {
    const int x = wave * 16 + g * 4 + rr;
    oof[rr] = (unsigned)(b * DX + x) * (unsigned)T * KC + c;
  }

  for (int t = 0; t < T; ++t) {
    // ---- X = m@z - h ; R = relu(X) ; zacc += n@R  (4 indep acc chains) ----
    float4v acc[4];
    acc[0] = (wave == 0) ? hzf : (float4v){0.f, 0.f, 0.f, 0.f};  // fold hz
    acc[1] = (float4v){0.f, 0.f, 0.f, 0.f};
    acc[2] = (float4v){0.f, 0.f, 0.f, 0.f};
    acc[3] = (float4v){0.f, 0.f, 0.f, 0.f};
#pragma unroll
    for (int i = 0; i < ITER; ++i) {
      float4v xv = mfma_bf16(mf[i].s, zb.s, negH[i]);
      short4v R = pack_bf16x4(fmaxf(xv[0], 0.f), fmaxf(xv[1], 0.f),
                              fmaxf(xv[2], 0.f), fmaxf(xv[3], 0.f));
      acc[i & 3] = mfma_bf16(nf[i].s, R, acc[i & 3]);
    }
    const float4v zp = (acc[0] + acc[1]) + (acc[2] + acc[3]);

    // ---- cross-wave reduce (double-buffered, 1 barrier/step) ----
    part[t & 1][wave][lane] = zp;
    __syncthreads();
    float4v tot;
    {
      const float4v p0 = part[t & 1][0][lane];
      const float4v p1 = part[t & 1][1][lane];
      const float4v p2 = part[t & 1][2][lane];
      const float4v p3 = part[t & 1][3][lane];
      const float4v p4 = part[t & 1][4][lane];
      const float4v p5 = part[t & 1][5][lane];
      const float4v p6 = part[t & 1][6][lane];
      const float4v p7 = part[t & 1][7][lane];
      tot = ((p0 + p1) + (p2 + p3)) + ((p4 + p5) + (p6 + p7));
    }

    // z' = A*z + tot   (hz folded into wave0 partial; identical in all waves)
#pragma unroll
    for (int j = 0; j < 4; ++j)
      zf[j] = fmaf(Af[j], zf[j], tot[j]);
    zb.s = pack_bf16x4(zf[0], zf[1], zf[2], zf[3]);

    // ---- fused readout: out[b, x, t, k] = BobsT@z' + Bias ----
    {
      float4v o = mfma_bf16(bobsF.s, zb.s, biasF);
      const unsigned tk = (unsigned)t * KC;
#pragma unroll
      for (int rr = 0; rr < 4; ++rr)
        out[oof[rr] + tk] = o[rr];
    }
  }
}

extern "C" void kernel_launch(void* const* d_in, const int* in_sizes, int n_in,
                              void* d_out, int out_size, void* d_ws, size_t ws_size,
                              hipStream_t stream) {
  const float* z0   = (const float*)d_in[0];
  const float* A    = (const float*)d_in[1];
  const float* nmat = (const float*)d_in[2];
  const float* mmat = (const float*)d_in[3];
  const float* h    = (const float*)d_in[4];
  const float* hz   = (const float*)d_in[5];
  const float* Bobs = (const float*)d_in[6];
  const float* Bias = (const float*)d_in[7];
  const int*   T    = (const int*)d_in[8];
  (void)in_sizes; (void)n_in; (void)out_size; (void)d_ws; (void)ws_size;
  lrrnn_fused<<<dim3(BB), dim3(64 * NW), 0, stream>>>(
      z0, A, nmat, mmat, h, hz, Bobs, Bias, T, (float*)d_out);
}